// Round 5
// baseline (182.958 us; speedup 1.0000x reference)
//
#include <hip/hip_runtime.h>
#include <hip/hip_bf16.h>

typedef __attribute__((ext_vector_type(8))) short s16x8;
typedef __attribute__((ext_vector_type(4))) float f32x4;
typedef __attribute__((ext_vector_type(4))) unsigned int u32x4;

#define MFMA(a,b,c) __builtin_amdgcn_mfma_f32_16x16x32_bf16((a),(b),(c),0,0,0)

__device__ __forceinline__ unsigned short bf16_rne(float f){
  unsigned int u = __float_as_uint(f);
  return (unsigned short)((u + 0x7FFFu + ((u >> 16) & 1u)) >> 16);
}
__device__ __forceinline__ float bf16_f32(unsigned short h){
  return __uint_as_float(((unsigned int)h) << 16);
}
__device__ __forceinline__ void split_hl(float f, short& hi, short& lo){
  unsigned short h = bf16_rne(f);
  float rem = f - bf16_f32(h);
  hi = (short)h;
  lo = (short)bf16_rne(rem);
}

// packed f32x2 -> bf16x2 (RNE on gfx950); D[15:0]=cvt(a), D[31:16]=cvt(b)
__device__ __forceinline__ unsigned int cvt_pk_bf16(float a, float b){
  unsigned int r;
  asm("v_cvt_pk_bf16_f32 %0, %1, %2" : "=v"(r) : "v"(a), "v"(b));
  return r;
}

// build hi/lo bf16 A-fragments from 8 consecutive fp32 values (cvt_pk path)
__device__ __forceinline__ void build_frag(const float* p, s16x8& fh, s16x8& fl){
  float4 v0 = *(const float4*)p;
  float4 v1 = *(const float4*)(p + 4);
  float vv[8] = {v0.x, v0.y, v0.z, v0.w, v1.x, v1.y, v1.z, v1.w};
  u32x4 th, tl;
  #pragma unroll
  for(int q = 0; q < 4; ++q){
    unsigned int h2 = cvt_pk_bf16(vv[2*q], vv[2*q+1]);
    float r0 = vv[2*q]     - __uint_as_float(h2 << 16);
    float r1 = vv[2*q + 1] - __uint_as_float(h2 & 0xffff0000u);
    th[q] = h2;
    tl[q] = cvt_pk_bf16(r0, r1);
  }
  fh = __builtin_bit_cast(s16x8, th);
  fl = __builtin_bit_cast(s16x8, tl);
}

__device__ __forceinline__ float sigm(float x){
  return __builtin_amdgcn_rcpf(1.0f + __expf(-x));
}
__device__ __forceinline__ float tanh_fast(float x){
  return 1.0f - 2.0f * __builtin_amdgcn_rcpf(__expf(2.0f * x) + 1.0f);
}

// ---------------------------------------------------------------------------
// Kernel 0: pack weights into fragment-ordered split-bf16 planes (once).
// ---------------------------------------------------------------------------
__global__ __launch_bounds__(256) void pack_kernel(
    const float* __restrict__ W1, const float* __restrict__ W2,
    const float* __restrict__ Wf, const float* __restrict__ Wb,
    unsigned short* __restrict__ w1p, unsigned short* __restrict__ w2p,
    unsigned short* __restrict__ wfp, unsigned short* __restrict__ wbp)
{
  int id = blockIdx.x * 256 + threadIdx.x;
  if(id < 8192){
    int t = id;
    int j = t & 7, lane = (t >> 3) & 63, nt = (t >> 9) & 3, kk = t >> 11;
    int k = kk * 32 + 8 * (lane >> 4) + j;
    int col = nt * 16 + (lane & 15);
    short h, l; split_hl(W1[k * 64 + col], h, l);
    w1p[t] = (unsigned short)h; w1p[8192 + t] = (unsigned short)l;
  } else if(id < 14336){
    int t = id - 8192;
    int j = t & 7, lane = (t >> 3) & 63, nt = (t >> 9) & 3, kk = t >> 11;
    int k = kk * 32 + 8 * (lane >> 4) + j;
    int col = nt * 16 + (lane & 15);
    short h, l; split_hl(W2[k * 64 + col], h, l);
    w2p[t] = (unsigned short)h; w2p[6144 + t] = (unsigned short)l;
  } else if(id < 47104){
    int t = id - 14336;
    int j = t & 7, lane = (t >> 3) & 63, dj = (t >> 9) & 3, kk = (t >> 11) & 3, gi = t >> 13;
    int k = kk * 32 + 8 * (lane >> 4) + j;
    int col = gi * 64 + dj * 16 + (lane & 15);
    short h, l; split_hl(Wf[k * 256 + col], h, l);
    wfp[t] = (unsigned short)h; wfp[32768 + t] = (unsigned short)l;
  } else if(id < 79872){
    int t = id - 47104;
    int j = t & 7, lane = (t >> 3) & 63, dj = (t >> 9) & 3, kk = (t >> 11) & 3, gi = t >> 13;
    int k = kk * 32 + 8 * (lane >> 4) + j;
    int col = gi * 64 + dj * 16 + (lane & 15);
    short h, l; split_hl(Wb[k * 256 + col], h, l);
    wbp[t] = (unsigned short)h; wbp[32768 + t] = (unsigned short)l;
  }
}

// ---------------------------------------------------------------------------
// Kernel 1: trunk.
// ---------------------------------------------------------------------------
__global__ __launch_bounds__(256) void trunk_kernel(
    const float* __restrict__ obs, const float* __restrict__ actg,
    const float* __restrict__ b1, const float* __restrict__ g1, const float* __restrict__ be1,
    const float* __restrict__ b2, const float* __restrict__ g2, const float* __restrict__ be2,
    const unsigned short* __restrict__ w1p, const unsigned short* __restrict__ w2p,
    unsigned short* __restrict__ x2h, unsigned short* __restrict__ x2l)
{
  __shared__ __align__(16) float x1_t[64][68];

  const int tid = threadIdx.x;
  const int r0 = blockIdx.x * 64;
  const int w = tid >> 6, lane = tid & 63;
  const int l15 = lane & 15, l4 = lane >> 4;

  float b1v[4], g1v[4], be1v[4], b2v[4], g2v[4], be2v[4];
  #pragma unroll
  for(int nt = 0; nt < 4; ++nt){
    int col = nt * 16 + l15;
    b1v[nt] = b1[col]; g1v[nt] = g1[col]; be1v[nt] = be1[col];
    b2v[nt] = b2[col]; g2v[nt] = g2[col]; be2v[nt] = be2[col];
  }

  f32x4 acc1[4] = {{0,0,0,0},{0,0,0,0},{0,0,0,0},{0,0,0,0}};
  #pragma unroll
  for(int kk = 0; kk < 4; ++kk){
    s16x8 ah, al;
    build_frag(&obs[(size_t)(r0 + w * 16 + l15) * 128 + 8 * l4 + 32 * kk], ah, al);
    #pragma unroll
    for(int nt = 0; nt < 4; ++nt){
      s16x8 bh = *(const s16x8*)&w1p[(kk * 2048 + nt * 512) + lane * 8];
      s16x8 bl = *(const s16x8*)&w1p[8192 + (kk * 2048 + nt * 512) + lane * 8];
      acc1[nt] = MFMA(ah, bh, acc1[nt]);
      acc1[nt] = MFMA(ah, bl, acc1[nt]);
      acc1[nt] = MFMA(al, bh, acc1[nt]);
    }
  }

  #pragma unroll
  for(int r = 0; r < 4; ++r){
    float v[4];
    #pragma unroll
    for(int nt = 0; nt < 4; ++nt) v[nt] = acc1[nt][r] + b1v[nt];
    float s = (v[0] + v[1]) + (v[2] + v[3]);
    #pragma unroll
    for(int mm = 1; mm < 16; mm <<= 1) s += __shfl_xor(s, mm);
    float mean = s * (1.0f / 64.0f);
    float d[4]; float q = 0.f;
    #pragma unroll
    for(int nt = 0; nt < 4; ++nt){ d[nt] = v[nt] - mean; q += d[nt] * d[nt]; }
    #pragma unroll
    for(int mm = 1; mm < 16; mm <<= 1) q += __shfl_xor(q, mm);
    float rstd = rsqrtf(q * (1.0f / 64.0f) + 1e-12f);
    int row = w * 16 + l4 * 4 + r;
    #pragma unroll
    for(int nt = 0; nt < 4; ++nt)
      x1_t[row][nt * 16 + l15] = fmaxf(0.f, d[nt] * rstd * g1v[nt] + be1v[nt]);
  }
  __syncthreads();

  f32x4 acc2[4] = {{0,0,0,0},{0,0,0,0},{0,0,0,0},{0,0,0,0}};
  #pragma unroll
  for(int kk = 0; kk < 3; ++kk){
    s16x8 ah, al;
    if(kk < 2) build_frag(&x1_t[w * 16 + l15][8 * l4 + 32 * kk], ah, al);
    else       build_frag(&actg[(size_t)(r0 + w * 16 + l15) * 32 + 8 * l4], ah, al);
    #pragma unroll
    for(int nt = 0; nt < 4; ++nt){
      s16x8 bh = *(const s16x8*)&w2p[(kk * 2048 + nt * 512) + lane * 8];
      s16x8 bl = *(const s16x8*)&w2p[6144 + (kk * 2048 + nt * 512) + lane * 8];
      acc2[nt] = MFMA(ah, bh, acc2[nt]);
      acc2[nt] = MFMA(ah, bl, acc2[nt]);
      acc2[nt] = MFMA(al, bh, acc2[nt]);
    }
  }

  #pragma unroll
  for(int r = 0; r < 4; ++r){
    float v[4];
    #pragma unroll
    for(int nt = 0; nt < 4; ++nt) v[nt] = acc2[nt][r] + b2v[nt];
    float s = (v[0] + v[1]) + (v[2] + v[3]);
    #pragma unroll
    for(int mm = 1; mm < 16; mm <<= 1) s += __shfl_xor(s, mm);
    float mean = s * (1.0f / 64.0f);
    float d[4]; float q = 0.f;
    #pragma unroll
    for(int nt = 0; nt < 4; ++nt){ d[nt] = v[nt] - mean; q += d[nt] * d[nt]; }
    #pragma unroll
    for(int mm = 1; mm < 16; mm <<= 1) q += __shfl_xor(q, mm);
    float rstd = rsqrtf(q * (1.0f / 64.0f) + 1e-12f);
    size_t rowg = (size_t)(r0 + w * 16 + l4 * 4 + r);
    float xv[4];
    #pragma unroll
    for(int nt = 0; nt < 4; ++nt) xv[nt] = fmaxf(0.f, d[nt] * rstd * g2v[nt] + be2v[nt]);
    unsigned int ph01 = cvt_pk_bf16(xv[0], xv[1]);
    float q0 = xv[0] - __uint_as_float(ph01 << 16);
    float q1 = xv[1] - __uint_as_float(ph01 & 0xffff0000u);
    unsigned int pl01 = cvt_pk_bf16(q0, q1);
    unsigned int ph23 = cvt_pk_bf16(xv[2], xv[3]);
    float q2 = xv[2] - __uint_as_float(ph23 << 16);
    float q3 = xv[3] - __uint_as_float(ph23 & 0xffff0000u);
    unsigned int pl23 = cvt_pk_bf16(q2, q3);
    x2h[rowg * 64 +  0 + l15] = (unsigned short)ph01;
    x2h[rowg * 64 + 16 + l15] = (unsigned short)(ph01 >> 16);
    x2h[rowg * 64 + 32 + l15] = (unsigned short)ph23;
    x2h[rowg * 64 + 48 + l15] = (unsigned short)(ph23 >> 16);
    x2l[rowg * 64 +  0 + l15] = (unsigned short)pl01;
    x2l[rowg * 64 + 16 + l15] = (unsigned short)(pl01 >> 16);
    x2l[rowg * 64 + 32 + l15] = (unsigned short)pl23;
    x2l[rowg * 64 + 48 + l15] = (unsigned short)(pl23 >> 16);
  }
}

// ---------------------------------------------------------------------------
// Kernel 2: LSTM scan + fused head.  16 sequences / block, 256 threads
// (4 waves = dj col-slices).  W fragments pinned register-resident; 1 barrier
// per step; wx/wp dots folded into MFMA as an extra B-tile (wave dj=0 only).
// ---------------------------------------------------------------------------
__global__ __launch_bounds__(256, 2) void lstm_kernel(
    const unsigned short* __restrict__ x2h, const unsigned short* __restrict__ x2l,
    const unsigned short* __restrict__ wfp, const unsigned short* __restrict__ wbp,
    const float* __restrict__ bfv, const float* __restrict__ bbv,
    const float* __restrict__ wx, const float* __restrict__ wp,
    const float* __restrict__ bx, const float* __restrict__ bp,
    const float* __restrict__ gp, const float* __restrict__ bep,
    const float* __restrict__ W3, const float* __restrict__ b3,
    float* __restrict__ out)
{
  __shared__ __align__(16) unsigned short h_h[2][16][72];
  __shared__ __align__(16) unsigned short h_l[2][16][72];
  __shared__ float xs_sh[16][64];
  __shared__ float ps_sh[16][64];
  __shared__ float W3s[64][64];
  __shared__ float p_sh[4][64];

  const int tid = threadIdx.x;
  const int dir = blockIdx.y;
  const int b0 = blockIdx.x * 16;
  const unsigned short* wpk  = dir ? wbp : wfp;
  const float* bias = dir ? bbv : bfv;

  const int w = tid >> 6, lane = tid & 63, l15 = lane & 15, l4 = lane >> 4;
  const int dj = w;

  float biasv[4];
  #pragma unroll
  for(int gi = 0; gi < 4; ++gi) biasv[gi] = bias[gi * 64 + dj * 16 + l15];
  biasv[2] += 1.0f;                       // forget_bias folded in

  // W B-fragments (hi/lo), pinned register-resident for all 64 steps.
  s16x8 Bh[4][4], Bl[4][4];
  #pragma unroll
  for(int gi = 0; gi < 4; ++gi){
    #pragma unroll
    for(int kk = 0; kk < 4; ++kk){
      int off = ((gi * 4 + kk) * 4 + dj) * 512 + lane * 8;
      Bh[gi][kk] = *(const s16x8*)&wpk[off];
      Bl[gi][kk] = *(const s16x8*)&wpk[32768 + off];
      asm volatile("" : "+v"(Bh[gi][kk]), "+v"(Bl[gi][kk]));
    }
  }

  // extra B-tile for the wx/wp dots: cols {wx_hi, wx_lo, wp_hi, wp_lo, 0...}
  s16x8 Bx[2];
  #pragma unroll
  for(int kk = 0; kk < 2; ++kk){
    #pragma unroll
    for(int j = 0; j < 8; ++j){
      int k = kk * 32 + 8 * l4 + j;
      short xh, xl, ph, pl;
      split_hl(wx[k], xh, xl);
      split_hl(wp[k], ph, pl);
      short sel = (l15 == 0) ? xh : (l15 == 1) ? xl : (l15 == 2) ? ph : (l15 == 3) ? pl : (short)0;
      Bx[kk][j] = sel;
    }
  }

  // stage W3 (head), zero h buffer 0
  #pragma unroll
  for(int i = 0; i < 4; ++i)
    *(float4*)&W3s[0][tid * 16 + i * 4] = *(const float4*)&W3[tid * 16 + i * 4];
  for(int i = tid; i < 16 * 72; i += 256){
    (&h_h[0][0][0])[i] = 0; (&h_l[0][0][0])[i] = 0;
  }

  // per-lane global x base: seq = b0+l15, k-chunk = 8*l4 (+32 for kk=1)
  const unsigned short* xbh = x2h + (size_t)(b0 + l15) * 4096 + 8 * l4;
  const unsigned short* xbl = x2l + (size_t)(b0 + l15) * 4096 + 8 * l4;

  int t0 = dir ? 63 : 0;
  int t1 = dir ? 62 : 1;
  s16x8 xah  = *(const s16x8*)&xbh[t0 * 64];
  s16x8 xah2 = *(const s16x8*)&xbh[t0 * 64 + 32];
  s16x8 xal  = *(const s16x8*)&xbl[t0 * 64];
  s16x8 xal2 = *(const s16x8*)&xbl[t0 * 64 + 32];
  s16x8 xbhr = *(const s16x8*)&xbh[t1 * 64];
  s16x8 xbh2 = *(const s16x8*)&xbh[t1 * 64 + 32];
  s16x8 xblr = *(const s16x8*)&xbl[t1 * 64];
  s16x8 xbl2 = *(const s16x8*)&xbl[t1 * 64 + 32];

  float c[4] = {0.f, 0.f, 0.f, 0.f};

  __syncthreads();   // h zero + W3 staged

  auto lstm_step = [&](s16x8& XH0, s16x8& XH1, s16x8& XL0, s16x8& XL1, int tau){
    const int cb = tau & 1, nb = cb ^ 1;
    // h A-fragments from current buffer
    s16x8 Ahh0 = *(const s16x8*)&h_h[cb][l15][8 * l4];
    s16x8 Ahh1 = *(const s16x8*)&h_h[cb][l15][8 * l4 + 32];
    s16x8 Ahl0 = *(const s16x8*)&h_l[cb][l15][8 * l4];
    s16x8 Ahl1 = *(const s16x8*)&h_l[cb][l15][8 * l4 + 32];
    f32x4 acc[4];
    #pragma unroll
    for(int gi = 0; gi < 4; ++gi)
      acc[gi] = (f32x4){biasv[gi], biasv[gi], biasv[gi], biasv[gi]};
    __builtin_amdgcn_s_setprio(1);
    #pragma unroll
    for(int gi = 0; gi < 4; ++gi){
      acc[gi] = MFMA(XH0, Bh[gi][0], acc[gi]);
      acc[gi] = MFMA(XH0, Bl[gi][0], acc[gi]);
      acc[gi] = MFMA(XL0, Bh[gi][0], acc[gi]);
      acc[gi] = MFMA(XH1, Bh[gi][1], acc[gi]);
      acc[gi] = MFMA(XH1, Bl[gi][1], acc[gi]);
      acc[gi] = MFMA(XL1, Bh[gi][1], acc[gi]);
    }
    __builtin_amdgcn_s_setprio(0);
    // prefetch x for step tau+2 into the just-consumed registers
    {
      int tf = tau + 2; if(tf > 63) tf = 63;
      int tn = dir ? 63 - tf : tf;
      XH0 = *(const s16x8*)&xbh[tn * 64];
      XH1 = *(const s16x8*)&xbh[tn * 64 + 32];
      XL0 = *(const s16x8*)&xbl[tn * 64];
      XL1 = *(const s16x8*)&xbl[tn * 64 + 32];
    }
    f32x4 accd = {0.f, 0.f, 0.f, 0.f};
    __builtin_amdgcn_s_setprio(1);
    #pragma unroll
    for(int gi = 0; gi < 4; ++gi){
      acc[gi] = MFMA(Ahh0, Bh[gi][2], acc[gi]);
      acc[gi] = MFMA(Ahh0, Bl[gi][2], acc[gi]);
      acc[gi] = MFMA(Ahl0, Bh[gi][2], acc[gi]);
      acc[gi] = MFMA(Ahh1, Bh[gi][3], acc[gi]);
      acc[gi] = MFMA(Ahh1, Bl[gi][3], acc[gi]);
      acc[gi] = MFMA(Ahl1, Bh[gi][3], acc[gi]);
    }
    if(dj == 0){
      accd = MFMA(Ahh0, Bx[0], accd);
      accd = MFMA(Ahl0, Bx[0], accd);
      accd = MFMA(Ahh1, Bx[1], accd);
      accd = MFMA(Ahl1, Bx[1], accd);
    }
    __builtin_amdgcn_s_setprio(0);
    // write dots of h_{tau-1} (xs = col0+col1, ps = col2+col3)
    if(dj == 0 && tau > 0){
      int tp = dir ? 64 - tau : tau - 1;
      #pragma unroll
      for(int r = 0; r < 4; ++r){
        float v = accd[r] + __shfl_xor(accd[r], 1);
        int s = l4 * 4 + r;
        if(l15 == 0) xs_sh[s][tp] = v;
        else if(l15 == 2) ps_sh[s][tp] = v;
      }
    }
    // gates + state update (order i, j, f, o)
    float hv[4];
    #pragma unroll
    for(int r = 0; r < 4; ++r){
      float zi = acc[0][r];
      float zj = acc[1][r];
      float zf = acc[2][r];
      float zo = acc[3][r];
      float cf = c[r] * sigm(zf) + sigm(zi) * tanh_fast(zj);
      c[r] = cf;
      hv[r] = tanh_fast(cf) * sigm(zo);
    }
    // write h (split via cvt_pk) into next buffer
    {
      unsigned int ph01 = cvt_pk_bf16(hv[0], hv[1]);
      float q0 = hv[0] - __uint_as_float(ph01 << 16);
      float q1 = hv[1] - __uint_as_float(ph01 & 0xffff0000u);
      unsigned int pl01 = cvt_pk_bf16(q0, q1);
      unsigned int ph23 = cvt_pk_bf16(hv[2], hv[3]);
      float q2 = hv[2] - __uint_as_float(ph23 << 16);
      float q3 = hv[3] - __uint_as_float(ph23 & 0xffff0000u);
      unsigned int pl23 = cvt_pk_bf16(q2, q3);
      int sb = l4 * 4, col = dj * 16 + l15;
      h_h[nb][sb + 0][col] = (unsigned short)ph01;
      h_h[nb][sb + 1][col] = (unsigned short)(ph01 >> 16);
      h_h[nb][sb + 2][col] = (unsigned short)ph23;
      h_h[nb][sb + 3][col] = (unsigned short)(ph23 >> 16);
      h_l[nb][sb + 0][col] = (unsigned short)pl01;
      h_l[nb][sb + 1][col] = (unsigned short)(pl01 >> 16);
      h_l[nb][sb + 2][col] = (unsigned short)pl23;
      h_l[nb][sb + 3][col] = (unsigned short)(pl23 >> 16);
    }
    __syncthreads();
  };

  for(int tau = 0; tau < 64; tau += 2){
    lstm_step(xah, xah2, xal, xal2, tau);
    lstm_step(xbhr, xbh2, xblr, xbl2, tau + 1);
  }

  // flush: dots of h_63 (in buffer 0 after step 63's write+barrier)
  if(dj == 0){
    s16x8 Ahh0 = *(const s16x8*)&h_h[0][l15][8 * l4];
    s16x8 Ahh1 = *(const s16x8*)&h_h[0][l15][8 * l4 + 32];
    s16x8 Ahl0 = *(const s16x8*)&h_l[0][l15][8 * l4];
    s16x8 Ahl1 = *(const s16x8*)&h_l[0][l15][8 * l4 + 32];
    f32x4 accd = {0.f, 0.f, 0.f, 0.f};
    accd = MFMA(Ahh0, Bx[0], accd);
    accd = MFMA(Ahl0, Bx[0], accd);
    accd = MFMA(Ahh1, Bx[1], accd);
    accd = MFMA(Ahl1, Bx[1], accd);
    int tp = dir ? 0 : 63;
    #pragma unroll
    for(int r = 0; r < 4; ++r){
      float v = accd[r] + __shfl_xor(accd[r], 1);
      int s = l4 * 4 + r;
      if(l15 == 0) xs_sh[s][tp] = v;
      else if(l15 == 2) ps_sh[s][tp] = v;
    }
  }
  __syncthreads();

  // ---- fused head ----
  const float bxv = bx[0], bpv = bp[0];
  #pragma unroll
  for(int r = 0; r < 4; ++r){
    int s = w * 4 + r;
    float xsv = xs_sh[s][lane] + bxv;
    float psv = ps_sh[s][lane] + bpv;
    float sum = psv;
    #pragma unroll
    for(int mm = 1; mm < 64; mm <<= 1) sum += __shfl_xor(sum, mm);
    float mean = sum * (1.f / 64.f);
    float d = psv - mean;
    float q = d * d;
    #pragma unroll
    for(int mm = 1; mm < 64; mm <<= 1) q += __shfl_xor(q, mm);
    float rstd = rsqrtf(q * (1.f / 64.f) + 1e-12f);
    float p = fmaxf(0.f, d * rstd * gp[lane] + bep[lane]);
    p_sh[w][lane] = p;
    float logit = b3[lane];
    #pragma unroll 8
    for(int t = 0; t < 64; ++t) logit += p_sh[w][t] * W3s[t][lane];
    float mx = logit;
    #pragma unroll
    for(int mm = 1; mm < 64; mm <<= 1) mx = fmaxf(mx, __shfl_xor(mx, mm));
    float e = __expf(logit - mx);
    float se = e;
    #pragma unroll
    for(int mm = 1; mm < 64; mm <<= 1) se += __shfl_xor(se, mm);
    float contrib = (e / se) * xsv;
    #pragma unroll
    for(int mm = 1; mm < 64; mm <<= 1) contrib += __shfl_xor(contrib, mm);
    if(lane == 0) out[(size_t)dir * 4096 + b0 + s] = contrib;
  }
}

extern "C" void kernel_launch(void* const* d_in, const int* in_sizes, int n_in,
                              void* d_out, int out_size, void* d_ws, size_t ws_size,
                              hipStream_t stream)
{
  (void)in_sizes; (void)n_in; (void)out_size; (void)ws_size;
  const float* obs = (const float*)d_in[0];
  const float* act = (const float*)d_in[1];
  const float* W1  = (const float*)d_in[2];
  const float* b1  = (const float*)d_in[3];
  const float* g1  = (const float*)d_in[4];
  const float* be1 = (const float*)d_in[5];
  const float* W2  = (const float*)d_in[6];
  const float* b2  = (const float*)d_in[7];
  const float* g2  = (const float*)d_in[8];
  const float* be2 = (const float*)d_in[9];
  const float* Wf  = (const float*)d_in[10];
  const float* bfv = (const float*)d_in[11];
  const float* Wb  = (const float*)d_in[12];
  const float* bbv = (const float*)d_in[13];
  const float* wx  = (const float*)d_in[14];
  const float* bx  = (const float*)d_in[15];
  const float* wp  = (const float*)d_in[16];
  const float* bp  = (const float*)d_in[17];
  const float* gp  = (const float*)d_in[18];
  const float* bep = (const float*)d_in[19];
  const float* W3  = (const float*)d_in[20];
  const float* b3  = (const float*)d_in[21];

  unsigned short* x2h = (unsigned short*)d_ws;                 // 262144*64 shorts
  unsigned short* x2l = x2h + (size_t)262144 * 64;             // 262144*64 shorts
  unsigned short* w1p = x2l + (size_t)262144 * 64;             // 2*8192
  unsigned short* w2p = w1p + 2 * 8192;                        // 2*6144
  unsigned short* wfp = w2p + 2 * 6144;                        // 2*32768
  unsigned short* wbp = wfp + 2 * 32768;                       // 2*32768
  float* outf = (float*)d_out;

  pack_kernel<<<312, 256, 0, stream>>>(W1, W2, Wf, Wb, w1p, w2p, wfp, wbp);
  trunk_kernel<<<4096, 256, 0, stream>>>(obs, act, b1, g1, be1, b2, g2, be2, w1p, w2p, x2h, x2l);
  lstm_kernel<<<dim3(256, 2), 256, 0, stream>>>(x2h, x2l, wfp, wbp, bfv, bbv, wx, wp,
                                                bx, bp, gp, bep, W3, b3, outf);
}